// Round 6
// baseline (311.406 us; speedup 1.0000x reference)
//
#include <hip/hip_runtime.h>
#include <math.h>

// ---------- types ----------
typedef __bf16 bf16_t;
typedef bf16_t bf16x8 __attribute__((ext_vector_type(8)));
typedef float  f32x4  __attribute__((ext_vector_type(4)));
typedef unsigned short u16;
typedef u16 ushortx4 __attribute__((ext_vector_type(4)));
typedef unsigned long long u64;

#define MFMA16(a, b, c) __builtin_amdgcn_mfma_f32_16x16x32_bf16((a), (b), (c), 0, 0, 0)

__device__ __forceinline__ u16 f2bf(float f) {
    unsigned int u = __float_as_uint(f);
    u = (u + 0x7fffu + ((u >> 16) & 1u)) >> 16;
    return (u16)u;
}

__device__ __forceinline__ float bf2f(unsigned int u) {
    return __uint_as_float(u << 16);
}

// async global->LDS, 16B per lane; lds dest = wave-uniform base + lane*16
__device__ __forceinline__ void gld16(const u16* g, u16* l) {
    __builtin_amdgcn_global_load_lds(
        (const __attribute__((address_space(1))) void*)g,
        (__attribute__((address_space(3))) void*)l, 16, 0, 0);
}

// B=2, L=2048, D_MODEL=1024, H=16, DH=64, HB=32
// ws: qb 0..8M, kb 8..16M, vb 16..24M (dead after k_proj; po/pl reuse 0..17M)
//     wqt 24M wkt 26M wvt 28M wot 30M;
//     qh 32M (pre-scaled by log2e/8), kh 40M, vt 48M, ao 56M;
//     mask64 64M (dead before xb), xb 64M..80M fp32
//     po = ws+0 (bf16 partial O, [ks][hb][row][64], 8MB per ks)
//     pl = ws+16M (f32 partial l, [ks][hb][row], 512KB)

// ---------- fused fp32 -> bf16 for q,k,v ----------
__global__ __launch_bounds__(256) void k_cvt3(const float* __restrict__ q,
                                              const float* __restrict__ k,
                                              const float* __restrict__ v,
                                              u16* __restrict__ qb,
                                              u16* __restrict__ kb,
                                              u16* __restrict__ vb) {
    int i = blockIdx.x * 256 + threadIdx.x;
    int sel = blockIdx.y;
    const float* src = sel == 0 ? q : (sel == 1 ? k : v);
    u16* dst = sel == 0 ? qb : (sel == 1 ? kb : vb);
    float4 val = ((const float4*)src)[i];
    ushortx4 r;
    r[0] = f2bf(val.x); r[1] = f2bf(val.y); r[2] = f2bf(val.z); r[3] = f2bf(val.w);
    ((ushortx4*)dst)[i] = r;
}

// ---------- transpose+convert the 3 qkv weights: [48 z][1024][64] -> [z][64][1024] ----------
__global__ __launch_bounds__(256) void k_tcvt3(const float* __restrict__ w_q,
                                               const float* __restrict__ w_k,
                                               const float* __restrict__ w_v,
                                               u16* __restrict__ wqt,
                                               u16* __restrict__ wkt,
                                               u16* __restrict__ wvt) {
    __shared__ float tile[32][33];
    int z = blockIdx.z, h = z & 15, sel = z >> 4;
    const float* src = (sel == 0 ? w_q : (sel == 1 ? w_k : w_v));
    u16* dst = (sel == 0 ? wqt : (sel == 1 ? wkt : wvt));
    int r0 = blockIdx.x * 32, c0 = blockIdx.y * 32;
    int tx = threadIdx.x & 31, ty = threadIdx.x >> 5;
    const float* s = src + ((size_t)h * 1024 + r0) * 64 + c0;
#pragma unroll
    for (int i = 0; i < 4; ++i) tile[ty + i * 8][tx] = s[(ty + i * 8) * 64 + tx];
    __syncthreads();
    u16* d = dst + ((size_t)h * 64 + c0) * 1024 + r0;
#pragma unroll
    for (int i = 0; i < 4; ++i) d[(ty + i * 8) * 1024 + tx] = f2bf(tile[tx][ty + i * 8]);
}

// ---------- transpose + convert w_o [1024][1024] -> [n][k] ----------
__global__ __launch_bounds__(256) void k_tcvt(const float* __restrict__ src,
                                              u16* __restrict__ dst, int R, int C) {
    __shared__ float tile[32][33];
    int r0 = blockIdx.x * 32, c0 = blockIdx.y * 32;
    int tx = threadIdx.x & 31, ty = threadIdx.x >> 5;
    const float* s = src + (size_t)r0 * C + c0;
#pragma unroll
    for (int i = 0; i < 4; ++i) tile[ty + i * 8][tx] = s[(ty + i * 8) * (size_t)C + tx];
    __syncthreads();
    u16* d = dst + (size_t)c0 * R + r0;
#pragma unroll
    for (int i = 0; i < 4; ++i) d[(ty + i * 8) * (size_t)R + tx] = f2bf(tile[tx][ty + i * 8]);
}

// ---------- mask bit-pack: mask[b][q][k] int32 -> mask64[b][kt][q] uint64 ----------
__global__ __launch_bounds__(256) void k_packmask(const int* __restrict__ mask,
                                                  u64* __restrict__ mask64) {
    int bid = blockIdx.x;  // 2 b x 512 q4 x 8 ktg
    int ktg = bid & 7, q4 = (bid >> 3) & 511, b = bid >> 12;
    int wave = threadIdx.x >> 6, lane = threadIdx.x & 63;
    int q = q4 * 4 + wave;
    const int* mp = mask + ((size_t)(b * 2048 + q)) * 2048 + ktg * 256 + lane;
#pragma unroll
    for (int i = 0; i < 4; ++i) {
        int m = mp[i * 64];
        u64 bal = __ballot(m != 0);
        if (lane == 0) mask64[((size_t)(b * 32 + ktg * 4 + i)) * 2048 + q] = bal;
    }
}

// ---------- GEMM core body (uses As, Bs u16* into shared) ----------
#define GEMM_CORE(Ablk, Bblk, ACC)                                                    \
    int c0 = wave * 2;                                                                \
    const u16* Ag0 = Ablk + (size_t)(c0 * 16 + l15) * 1024 + quad * 8;                \
    const u16* Ag1 = Ablk + (size_t)((c0 + 1) * 16 + l15) * 1024 + quad * 8;          \
    const u16* Bg0 = Bblk + (size_t)(c0 * 16 + l15) * 1024 + quad * 8;                \
    const u16* Bg1 = Bblk + (size_t)((c0 + 1) * 16 + l15) * 1024 + quad * 8;          \
    gld16(Ag0, As + c0 * 512); gld16(Ag1, As + (c0 + 1) * 512);                       \
    gld16(Bg0, Bs + c0 * 512); gld16(Bg1, Bs + (c0 + 1) * 512);                       \
    __syncthreads();                                                                  \
    int buf = 0;                                                                      \
    for (int ks = 0; ks < 32; ++ks) {                                                 \
        if (ks < 31) {                                                                \
            int k0 = (ks + 1) * 32;                                                   \
            gld16(Ag0 + k0, As + (buf ^ 1) * 4096 + c0 * 512);                        \
            gld16(Ag1 + k0, As + (buf ^ 1) * 4096 + (c0 + 1) * 512);                  \
            gld16(Bg0 + k0, Bs + (buf ^ 1) * 4096 + c0 * 512);                        \
            gld16(Bg1 + k0, Bs + (buf ^ 1) * 4096 + (c0 + 1) * 512);                  \
        }                                                                             \
        bf16x8 af[4], bfr[4];                                                         \
        _Pragma("unroll")                                                             \
        for (int i = 0; i < 4; ++i)                                                   \
            af[i] = *(const bf16x8*)(As + buf * 4096 + (wy * 4 + i) * 512 + lane * 8);\
        _Pragma("unroll")                                                             \
        for (int j = 0; j < 4; ++j)                                                   \
            bfr[j] = *(const bf16x8*)(Bs + buf * 4096 + (wx * 4 + j) * 512 + lane * 8);\
        _Pragma("unroll")                                                             \
        for (int i = 0; i < 4; ++i)                                                   \
            _Pragma("unroll")                                                         \
            for (int j = 0; j < 4; ++j) ACC[i][j] = MFMA16(af[i], bfr[j], ACC[i][j]); \
        __syncthreads();                                                              \
        buf ^= 1;                                                                     \
    }

// ---------- fused q/k/v projections, coalesced epilogue via LDS ----------
// z=0: qh (scaled by log2e/8), z=1: kh, z=2: vt = Wv@vb^T
__global__ __launch_bounds__(256) void k_proj(
    const u16* __restrict__ qb, const u16* __restrict__ kb, const u16* __restrict__ vb,
    const u16* __restrict__ wqt, const u16* __restrict__ wkt, const u16* __restrict__ wvt,
    u16* __restrict__ oq, u16* __restrict__ okh, u16* __restrict__ ovt) {
    __shared__ __align__(16) u16 smem[18432];
    u16* As = smem;
    u16* Bs = smem + 8192;
    int z = blockIdx.y, gx = blockIdx.x;
    int bm, bn;
    const u16 *A, *B;
    if (z == 0)      { bm = gx >> 3; bn = gx & 7; A = qb; B = wqt; }
    else if (z == 1) { bm = gx >> 3; bn = gx & 7; A = kb; B = wkt; }
    else             { bm = gx & 7; bn = gx >> 3; A = wvt; B = vb; }
    A += (size_t)bm * 128 * 1024;
    B += (size_t)bn * 128 * 1024;
    int tid = threadIdx.x, wave = tid >> 6, lane = tid & 63;
    int wy = wave >> 1, wx = wave & 1, l15 = lane & 15, quad = lane >> 4;
    f32x4 acc[4][4] = {};
    GEMM_CORE(A, B, acc)
    // epilogue: wave tile 64x64 -> LDS (stride 72) -> coalesced dwordx4 stores
    u16* ep = smem + wave * 4608;
    float mulf = (z == 0) ? 0.18033688011112042f : 1.0f;
#pragma unroll
    for (int i = 0; i < 4; ++i)
#pragma unroll
        for (int j = 0; j < 4; ++j)
#pragma unroll
            for (int r = 0; r < 4; ++r)
                ep[(i * 16 + quad * 4 + r) * 72 + j * 16 + l15] = f2bf(acc[i][j][r] * mulf);
    int rl = lane >> 3, cg = lane & 7;
    if (z < 2) {
        int hh = bn * 2 + wx;
        int m0 = bm * 128 + wy * 64;
        int bb = m0 >> 11, l0 = m0 & 2047;
        u16* O = (z ? okh : oq) + ((size_t)((hh * 2 + bb) * 2048 + l0)) * 64;
#pragma unroll
        for (int s = 0; s < 8; ++s) {
            int row = s * 8 + rl;
            uint4 v = *(const uint4*)(ep + row * 72 + cg * 8);
            *(uint4*)(O + (size_t)row * 64 + cg * 8) = v;
        }
    } else {
        int m0 = bm * 128 + wy * 64;   // e-global
        int hh = m0 >> 6;
        int n0 = bn * 128 + wx * 64;   // l-global
        int bb = n0 >> 11, l0 = n0 & 2047;
        u16* O = ovt + (size_t)(hh * 2 + bb) * 131072 + (size_t)(m0 & 63) * 2048 + l0;
#pragma unroll
        for (int s = 0; s < 8; ++s) {
            int row = s * 8 + rl;      // e within tile
            uint4 v = *(const uint4*)(ep + row * 72 + cg * 8);
            *(uint4*)(O + (size_t)row * 2048 + cg * 8) = v;
        }
    }
}

// ---------- output projection + bias + residual, 512 threads, 128x128 tile ----------
__global__ __launch_bounds__(512) void k_out(
    const u16* __restrict__ ao, const u16* __restrict__ wot,
    const float* __restrict__ bo, const float* __restrict__ resid,
    float* __restrict__ xb) {
    __shared__ __align__(16) u16 smem[18432];
    u16* As = smem;
    u16* Bs = smem + 8192;
    int gx = blockIdx.x, bm = gx >> 3, bn = gx & 7;
    const u16* A = ao + (size_t)bm * 128 * 1024;
    const u16* B = wot + (size_t)bn * 128 * 1024;
    int tid = threadIdx.x, wave = tid >> 6, lane = tid & 63;
    int wy = wave >> 2, wx = wave & 3, l15 = lane & 15, quad = lane >> 4;
    // staging: 8 waves, wave w stages A chunk w and B chunk w
    const u16* Ag = A + (size_t)(wave * 16 + l15) * 1024 + quad * 8;
    const u16* Bg = B + (size_t)(wave * 16 + l15) * 1024 + quad * 8;
    f32x4 acc[4][2] = {};
    gld16(Ag, As + wave * 512);
    gld16(Bg, Bs + wave * 512);
    __syncthreads();
    int buf = 0;
    for (int ks = 0; ks < 32; ++ks) {
        if (ks < 31) {
            int k0 = (ks + 1) * 32;
            gld16(Ag + k0, As + (buf ^ 1) * 4096 + wave * 512);
            gld16(Bg + k0, Bs + (buf ^ 1) * 4096 + wave * 512);
        }
        bf16x8 af[4], bfr[2];
#pragma unroll
        for (int i = 0; i < 4; ++i)
            af[i] = *(const bf16x8*)(As + buf * 4096 + (wy * 4 + i) * 512 + lane * 8);
#pragma unroll
        for (int j = 0; j < 2; ++j)
            bfr[j] = *(const bf16x8*)(Bs + buf * 4096 + (wx * 2 + j) * 512 + lane * 8);
#pragma unroll
        for (int i = 0; i < 4; ++i)
#pragma unroll
            for (int j = 0; j < 2; ++j) acc[i][j] = MFMA16(af[i], bfr[j], acc[i][j]);
        __syncthreads();
        buf ^= 1;
    }
    // epilogue: per wave 64x32 fp32, two passes of 32x32 via LDS (stride 36 f32)
    float* epf = (float*)smem + wave * 1152;
    int rl = lane >> 3, cg = lane & 7;
    int mbase = bm * 128 + wy * 64, nbase = bn * 128 + wx * 32;
#pragma unroll
    for (int cc = 0; cc < 2; ++cc) {
#pragma unroll
        for (int i2 = 0; i2 < 2; ++i2)
#pragma unroll
            for (int j = 0; j < 2; ++j)
#pragma unroll
                for (int r = 0; r < 4; ++r)
                    epf[(i2 * 16 + quad * 4 + r) * 36 + j * 16 + l15] =
                        acc[cc * 2 + i2][j][r];
#pragma unroll
        for (int s = 0; s < 4; ++s) {
            int row = s * 8 + rl;
            f32x4 v = *(const f32x4*)(epf + row * 36 + cg * 4);
            int m = mbase + cc * 32 + row, n = nbase + cg * 4;
            float4 rsd = *(const float4*)(resid + (size_t)m * 1024 + n);
            float4 bo4 = *(const float4*)(bo + n);
            float4 o;
            o.x = v[0] + bo4.x + rsd.x;
            o.y = v[1] + bo4.y + rsd.y;
            o.z = v[2] + bo4.z + rsd.z;
            o.w = v[3] + bo4.w + rsd.w;
            *(float4*)(xb + (size_t)m * 1024 + n) = o;
        }
    }
}

// ---------- flash attention: split-K, 32 Q-rows/wave, K/V frags register-cached ----------
// grid (8 qt, 32 hb, 2 ks), block 512 = 8 waves x 32 Q-rows = 256 rows; 16 kt per block
// Q pre-scaled by log2e/8 so p = exp2(st). Outputs UNNORMALIZED bf16 partial O + f32 l.
__global__ __launch_bounds__(512) void k_attn(
    const u16* __restrict__ qh, const u16* __restrict__ kh,
    const u16* __restrict__ vt, const u64* __restrict__ mask64,
    u16* __restrict__ po, float* __restrict__ pl) {
    int qt = blockIdx.x, hb = blockIdx.y, ksp = blockIdx.z;
    int b = hb & 1;
    int tid = threadIdx.x, wave = tid >> 6, lane = tid & 63;
    int l15 = lane & 15, quad = lane >> 4;

    __shared__ __align__(16) u16 Ks[2][4096], Vs[2][4096];
    __shared__ __align__(16) u16 Pb[8][16][72];

    int qrow0 = qt * 256 + wave * 32;
    const u16* Qp = qh + ((size_t)(hb * 2048) + qrow0 + l15) * 64 + quad * 8;
    bf16x8 qf[2][2];
    qf[0][0] = *(const bf16x8*)Qp;
    qf[0][1] = *(const bf16x8*)(Qp + 32);
    qf[1][0] = *(const bf16x8*)(Qp + 1024);
    qf[1][1] = *(const bf16x8*)(Qp + 1024 + 32);

    // staging: wave stages chunk `wave` of K and V (chunk c: rows (c>>1)*16, dcols (c&1)*32)
    int rC = (wave >> 1) * 16 + l15, dC = (wave & 1) * 32 + quad * 8;
    const u16* Kg = kh + (size_t)hb * 131072 + (size_t)ksp * 65536 + (size_t)rC * 64 + dC;
    const u16* Vg = vt + (size_t)hb * 131072 + (size_t)rC * 2048 + ksp * 1024 + dC;
    const u64* Mp = mask64 + (size_t)b * 65536 + (size_t)ksp * 32768 + qrow0 + l15;

    float l_lane[2] = {0.f, 0.f};
    f32x4 o[2][4] = {};

    gld16(Kg, &Ks[0][wave * 512]);
    gld16(Vg, &Vs[0][wave * 512]);
    u64 mw0 = Mp[0], mw1 = Mp[16];
    __syncthreads();
    int buf = 0;
    for (int kt = 0; kt < 16; ++kt) {
        u64 mwn0 = 0, mwn1 = 0;
        if (kt < 15) {
            gld16(Kg + (size_t)(kt + 1) * 4096, &Ks[buf ^ 1][wave * 512]);
            gld16(Vg + (size_t)(kt + 1) * 64, &Vs[buf ^ 1][wave * 512]);
            mwn0 = Mp[(size_t)(kt + 1) * 2048];
            mwn1 = Mp[(size_t)(kt + 1) * 2048 + 16];
        }
        // register-cache K and V fragments once, reuse for both Q halves
        bf16x8 kf[8], vf[8];
#pragma unroll
        for (int c = 0; c < 8; ++c) kf[c] = *(const bf16x8*)&Ks[buf][c * 512 + lane * 8];
#pragma unroll
        for (int c = 0; c < 8; ++c) vf[c] = *(const bf16x8*)&Vs[buf][c * 512 + lane * 8];
#pragma unroll
        for (int hf = 0; hf < 2; ++hf) {
            u64 mw = hf ? mw1 : mw0;
            // ---- S^T: lane = (qrow=l15, kcol = t*16 + quad*4 + r) ----
            f32x4 st[4] = {};
#pragma unroll
            for (int t = 0; t < 4; ++t) {
                st[t] = MFMA16(kf[t * 2], qf[hf][0], st[t]);
                st[t] = MFMA16(kf[t * 2 + 1], qf[hf][1], st[t]);
            }
            unsigned int w0 = (unsigned int)(mw >> (quad * 4));
            unsigned int w1 = (unsigned int)(mw >> (32 + quad * 4));
#pragma unroll
            for (int r = 0; r < 4; ++r) {
                st[0][r] = ((w0 >> r) & 1u) ? -3e30f : st[0][r];
                st[1][r] = ((w0 >> (16 + r)) & 1u) ? -3e30f : st[1][r];
                st[2][r] = ((w1 >> r) & 1u) ? -3e30f : st[2][r];
                st[3][r] = ((w1 >> (16 + r)) & 1u) ? -3e30f : st[3][r];
            }
            // ---- p = exp2(st), accumulate l, pack bf16 -> Pb ----
            float ll = 0.f;
#pragma unroll
            for (int t = 0; t < 4; ++t) {
                float p0 = __builtin_amdgcn_exp2f(st[t][0]);
                float p1 = __builtin_amdgcn_exp2f(st[t][1]);
                float p2 = __builtin_amdgcn_exp2f(st[t][2]);
                float p3 = __builtin_amdgcn_exp2f(st[t][3]);
                ll += (p0 + p1) + (p2 + p3);
                uint2 pk;
                pk.x = (__float_as_uint(p1) & 0xffff0000u) | (__float_as_uint(p0) >> 16);
                pk.y = (__float_as_uint(p3) & 0xffff0000u) | (__float_as_uint(p2) >> 16);
                *(uint2*)&Pb[wave][l15][t * 16 + quad * 4] = pk;
            }
            l_lane[hf] += ll;
            // ---- O += P @ V ----
#pragma unroll
            for (int kc = 0; kc < 2; ++kc) {
                bf16x8 pf = *(const bf16x8*)&Pb[wave][l15][kc * 32 + quad * 8];
#pragma unroll
                for (int t = 0; t < 4; ++t)
                    o[hf][t] = MFMA16(pf, vf[t * 2 + kc], o[hf][t]);
            }
        }
        mw0 = mwn0; mw1 = mwn1;
        __syncthreads();
        buf ^= 1;
    }
    // ---- store partial l + unnormalized partial O (coalesced via Pb) ----
    size_t rowbase = ((size_t)ksp * 32 + hb) * 2048 + qrow0;
    int rl = lane >> 3, cg = lane & 7;
#pragma unroll
    for (int hf = 0; hf < 2; ++hf) {
        float ls = l_lane[hf];
        ls += __shfl_xor(ls, 16, 64);
        ls += __shfl_xor(ls, 32, 64);
        if (quad == 0) pl[rowbase + hf * 16 + l15] = ls;
#pragma unroll
        for (int t = 0; t < 4; ++t)
#pragma unroll
            for (int r = 0; r < 4; ++r)
                Pb[wave][quad * 4 + r][t * 16 + l15] = f2bf(o[hf][t][r]);
#pragma unroll
        for (int s = 0; s < 2; ++s) {
            int row = s * 8 + rl;
            uint4 v = *(const uint4*)&Pb[wave][row][cg * 8];
            *(uint4*)(po + (rowbase + hf * 16 + row) * 64 + cg * 8) = v;
        }
    }
}

// ---------- split-K merge: ao = (po0+po1)/(l0+l1) ----------
__global__ __launch_bounds__(256) void k_amerge(const u16* __restrict__ po,
                                                const float* __restrict__ pl,
                                                u16* __restrict__ ao) {
    int bid = blockIdx.x;               // 32 hb x 64 row-chunks
    int hb = bid >> 6, rc = bid & 63;
    int h = hb >> 1, b = hb & 1;
    int tid = threadIdx.x;
    int r = tid >> 3, c = tid & 7;
    int row = rc * 32 + r;
    size_t i0 = ((size_t)hb * 2048 + row) * 64 + c * 8;
    uint4 a0 = *(const uint4*)(po + i0);
    uint4 a1 = *(const uint4*)(po + i0 + 4194304);
    float l0 = pl[(size_t)hb * 2048 + row];
    float l1 = pl[65536 + (size_t)hb * 2048 + row];
    float inv = 1.0f / (l0 + l1);
    unsigned int* pa0 = (unsigned int*)&a0;
    unsigned int* pa1 = (unsigned int*)&a1;
    uint4 out;
    unsigned int* po_ = (unsigned int*)&out;
#pragma unroll
    for (int i = 0; i < 4; ++i) {
        float lo = (bf2f(pa0[i] & 0xffffu) + bf2f(pa1[i] & 0xffffu)) * inv;
        float hi = (bf2f(pa0[i] >> 16) + bf2f(pa1[i] >> 16)) * inv;
        po_[i] = (unsigned int)f2bf(lo) | ((unsigned int)f2bf(hi) << 16);
    }
    *(uint4*)(ao + ((size_t)(b * 2048 + row)) * 1024 + h * 64 + c * 8) = out;
}

// ---------- layernorm (torch: std ddof=1, eps on std) ----------
__global__ __launch_bounds__(256) void k_ln(const float* __restrict__ x,
                                            const float* __restrict__ gamma,
                                            const float* __restrict__ beta,
                                            float* __restrict__ out) {
    int row = blockIdx.x;
    const float* xr = x + (size_t)row * 1024;
    float4 v = ((const float4*)xr)[threadIdx.x];
    float s = v.x + v.y + v.z + v.w;
    float ss = v.x * v.x + v.y * v.y + v.z * v.z + v.w * v.w;
#pragma unroll
    for (int off = 32; off; off >>= 1) {
        s += __shfl_down(s, off, 64);
        ss += __shfl_down(ss, off, 64);
    }
    __shared__ float sb[8];
    int wave = threadIdx.x >> 6, lane = threadIdx.x & 63;
    if (lane == 0) { sb[wave] = s; sb[4 + wave] = ss; }
    __syncthreads();
    s = sb[0] + sb[1] + sb[2] + sb[3];
    ss = sb[4] + sb[5] + sb[6] + sb[7];
    float mean = s * (1.0f / 1024.0f);
    float var = fmaxf((ss - 1024.0f * mean * mean) * (1.0f / 1023.0f), 0.f);
    float inv = 1.0f / (sqrtf(var) + 1e-3f);
    float4 g = ((const float4*)gamma)[threadIdx.x];
    float4 bt = ((const float4*)beta)[threadIdx.x];
    float4 o;
    o.x = (v.x - mean) * inv * g.x + bt.x;
    o.y = (v.y - mean) * inv * g.y + bt.y;
    o.z = (v.z - mean) * inv * g.z + bt.z;
    o.w = (v.w - mean) * inv * g.w + bt.w;
    ((float4*)(out + (size_t)row * 1024))[threadIdx.x] = o;
}

// ---------- launch ----------
extern "C" void kernel_launch(void* const* d_in, const int* in_sizes, int n_in,
                              void* d_out, int out_size, void* d_ws, size_t ws_size,
                              hipStream_t stream) {
    const float* v_in  = (const float*)d_in[0];
    const float* k_in  = (const float*)d_in[1];
    const float* q_in  = (const float*)d_in[2];
    const int*   mask  = (const int*)d_in[3];
    const float* w_q   = (const float*)d_in[4];
    const float* w_k   = (const float*)d_in[5];
    const float* w_v   = (const float*)d_in[6];
    const float* w_o   = (const float*)d_in[7];
    const float* b_o   = (const float*)d_in[8];
    const float* gamma = (const float*)d_in[9];
    const float* beta  = (const float*)d_in[10];
    float* out = (float*)d_out;

    char* ws = (char*)d_ws;
    const size_t MB = 1ull << 20;
    u16* qb  = (u16*)(ws + 0 * MB);
    u16* kb  = (u16*)(ws + 8 * MB);
    u16* vb  = (u16*)(ws + 16 * MB);
    u16* wqt = (u16*)(ws + 24 * MB);
    u16* wkt = (u16*)(ws + 26 * MB);
    u16* wvt = (u16*)(ws + 28 * MB);
    u16* wot = (u16*)(ws + 30 * MB);
    u16* qh  = (u16*)(ws + 32 * MB);
    u16* kh  = (u16*)(ws + 40 * MB);
    u16* vt  = (u16*)(ws + 48 * MB);
    u16* ao  = (u16*)(ws + 56 * MB);
    u64* mask64 = (u64*)(ws + 64 * MB);  // dead before xb written
    float* xb = (float*)(ws + 64 * MB);
    u16*   po = (u16*)(ws + 0 * MB);     // reuses qb/kb (dead after k_proj)
    float* pl = (float*)(ws + 16 * MB);  // reuses vb head (dead after k_proj)

    k_cvt3<<<dim3(4096, 3), dim3(256), 0, stream>>>(q_in, k_in, v_in, qb, kb, vb);
    k_tcvt3<<<dim3(32, 2, 48), dim3(256), 0, stream>>>(w_q, w_k, w_v, wqt, wkt, wvt);
    k_tcvt<<<dim3(32, 32), dim3(256), 0, stream>>>(w_o, wot, 1024, 1024);
    k_packmask<<<dim3(8192), dim3(256), 0, stream>>>(mask, mask64);
    k_proj<<<dim3(256, 3), dim3(256), 0, stream>>>(qb, kb, vb, wqt, wkt, wvt, qh, kh, vt);
    k_attn<<<dim3(8, 32, 2), dim3(512), 0, stream>>>(qh, kh, vt, mask64, po, pl);
    k_amerge<<<dim3(2048), dim3(256), 0, stream>>>(po, pl, ao);
    k_out<<<dim3(256), dim3(512), 0, stream>>>(ao, wot, b_o, k_in, xb);
    k_ln<<<dim3(4096), dim3(256), 0, stream>>>(xb, gamma, beta, out);
}

// Round 7
// 308.887 us; speedup vs baseline: 1.0082x; 1.0082x over previous
//
#include <hip/hip_runtime.h>
#include <math.h>

// ---------- types ----------
typedef __bf16 bf16_t;
typedef bf16_t bf16x8 __attribute__((ext_vector_type(8)));
typedef float  f32x4  __attribute__((ext_vector_type(4)));
typedef unsigned short u16;
typedef u16 ushortx4 __attribute__((ext_vector_type(4)));
typedef unsigned long long u64;

#define MFMA16(a, b, c) __builtin_amdgcn_mfma_f32_16x16x32_bf16((a), (b), (c), 0, 0, 0)

__device__ __forceinline__ u16 f2bf(float f) {
    unsigned int u = __float_as_uint(f);
    u = (u + 0x7fffu + ((u >> 16) & 1u)) >> 16;
    return (u16)u;
}

__device__ __forceinline__ float bf2f(unsigned int u) {
    return __uint_as_float(u << 16);
}

// async global->LDS, 16B per lane; lds dest = wave-uniform base + lane*16
__device__ __forceinline__ void gld16(const u16* g, u16* l) {
    __builtin_amdgcn_global_load_lds(
        (const __attribute__((address_space(1))) void*)g,
        (__attribute__((address_space(3))) void*)l, 16, 0, 0);
}

// B=2, L=2048, D_MODEL=1024, H=16, DH=64, HB=32
// ws map (MB):  [phase-aware reuse]
//  qb 0-8, kb 8-16, vb 16-24        (dead after k_proj)
//  wqt 24-26 wkt 26-28 wvt 28-30    (dead after k_proj)
//  wot 30-32                        (alive until k_out)
//  qh 32-40 (scaled by log2e/8), kh 40-48, vt 48-56 (dead after k_attn)
//  ao 56-64                          (alive until k_out)
//  mask64 64-65                      (dead after k_attn)
//  po 0-16 (over qb/kb), pl 16-17 (over vb)   [k_attn out, dead after k_amerge]
//  xp0 32-48 (over qh/kh), xp1 64-80 (over mask64)  [k_out partials -> k_ln]

// ---------- fused: fp32->bf16 cvt for q,k,v  +  mask bit-pack ----------
__global__ __launch_bounds__(256) void k_prep(const float* __restrict__ q,
                                              const float* __restrict__ k,
                                              const float* __restrict__ v,
                                              const int* __restrict__ mask,
                                              u16* __restrict__ qb,
                                              u16* __restrict__ kb,
                                              u16* __restrict__ vb,
                                              u64* __restrict__ mask64) {
    int bid = blockIdx.x;
    if (bid < 12288) {
        int sel = bid >> 12;                 // 0..2
        int i = (bid & 4095) * 256 + threadIdx.x;
        const float* src = sel == 0 ? q : (sel == 1 ? k : v);
        u16* dst = sel == 0 ? qb : (sel == 1 ? kb : vb);
        float4 val = ((const float4*)src)[i];
        ushortx4 r;
        r[0] = f2bf(val.x); r[1] = f2bf(val.y); r[2] = f2bf(val.z); r[3] = f2bf(val.w);
        ((ushortx4*)dst)[i] = r;
    } else {
        int b2 = bid - 12288;                // 2 b x 512 q4 x 8 ktg
        int ktg = b2 & 7, q4 = (b2 >> 3) & 511, b = b2 >> 12;
        int wave = threadIdx.x >> 6, lane = threadIdx.x & 63;
        int qq = q4 * 4 + wave;
        const int* mp = mask + ((size_t)(b * 2048 + qq)) * 2048 + ktg * 256 + lane;
#pragma unroll
        for (int i = 0; i < 4; ++i) {
            int m = mp[i * 64];
            u64 bal = __ballot(m != 0);
            if (lane == 0) mask64[((size_t)(b * 32 + ktg * 4 + i)) * 2048 + qq] = bal;
        }
    }
}

// ---------- fused weight transposes: w_q/w_k/w_v [h][1024][64] and w_o [1024][1024] ----------
__global__ __launch_bounds__(256) void k_prepw(const float* __restrict__ w_q,
                                               const float* __restrict__ w_k,
                                               const float* __restrict__ w_v,
                                               const float* __restrict__ w_o,
                                               u16* __restrict__ wqt,
                                               u16* __restrict__ wkt,
                                               u16* __restrict__ wvt,
                                               u16* __restrict__ wot) {
    __shared__ float tile[32][33];
    int bid = blockIdx.x;
    const float* src;
    u16* dst;
    int r0, c0, R, C;
    if (bid < 3072) {
        int x = bid & 31, y = (bid >> 5) & 1, z = bid >> 6;
        int h = z & 15, sel = z >> 4;
        src = (sel == 0 ? w_q : (sel == 1 ? w_k : w_v)) + (size_t)h * 65536;
        dst = (sel == 0 ? wqt : (sel == 1 ? wkt : wvt)) + (size_t)h * 65536;
        r0 = x * 32; c0 = y * 32; R = 1024; C = 64;
    } else {
        int t = bid - 3072;
        r0 = (t & 31) * 32; c0 = (t >> 5) * 32; R = 1024; C = 1024;
        src = w_o; dst = wot;
    }
    int tx = threadIdx.x & 31, ty = threadIdx.x >> 5;
    const float* s = src + ((size_t)r0) * C + c0;
#pragma unroll
    for (int i = 0; i < 4; ++i) tile[ty + i * 8][tx] = s[(ty + i * 8) * (size_t)C + tx];
    __syncthreads();
    u16* d = dst + ((size_t)c0) * R + r0;
#pragma unroll
    for (int i = 0; i < 4; ++i) d[(ty + i * 8) * (size_t)R + tx] = f2bf(tile[tx][ty + i * 8]);
}

// ---------- GEMM core body (uses As, Bs u16* into shared) ----------
#define GEMM_CORE(Ablk, Bblk, ACC)                                                    \
    int c0 = wave * 2;                                                                \
    const u16* Ag0 = Ablk + (size_t)(c0 * 16 + l15) * 1024 + quad * 8;                \
    const u16* Ag1 = Ablk + (size_t)((c0 + 1) * 16 + l15) * 1024 + quad * 8;          \
    const u16* Bg0 = Bblk + (size_t)(c0 * 16 + l15) * 1024 + quad * 8;                \
    const u16* Bg1 = Bblk + (size_t)((c0 + 1) * 16 + l15) * 1024 + quad * 8;          \
    gld16(Ag0, As + c0 * 512); gld16(Ag1, As + (c0 + 1) * 512);                       \
    gld16(Bg0, Bs + c0 * 512); gld16(Bg1, Bs + (c0 + 1) * 512);                       \
    __syncthreads();                                                                  \
    int buf = 0;                                                                      \
    for (int ks = 0; ks < 32; ++ks) {                                                 \
        if (ks < 31) {                                                                \
            int k0 = (ks + 1) * 32;                                                   \
            gld16(Ag0 + k0, As + (buf ^ 1) * 4096 + c0 * 512);                        \
            gld16(Ag1 + k0, As + (buf ^ 1) * 4096 + (c0 + 1) * 512);                  \
            gld16(Bg0 + k0, Bs + (buf ^ 1) * 4096 + c0 * 512);                        \
            gld16(Bg1 + k0, Bs + (buf ^ 1) * 4096 + (c0 + 1) * 512);                  \
        }                                                                             \
        bf16x8 af[4], bfr[4];                                                         \
        _Pragma("unroll")                                                             \
        for (int i = 0; i < 4; ++i)                                                   \
            af[i] = *(const bf16x8*)(As + buf * 4096 + (wy * 4 + i) * 512 + lane * 8);\
        _Pragma("unroll")                                                             \
        for (int j = 0; j < 4; ++j)                                                   \
            bfr[j] = *(const bf16x8*)(Bs + buf * 4096 + (wx * 4 + j) * 512 + lane * 8);\
        _Pragma("unroll")                                                             \
        for (int i = 0; i < 4; ++i)                                                   \
            _Pragma("unroll")                                                         \
            for (int j = 0; j < 4; ++j) ACC[i][j] = MFMA16(af[i], bfr[j], ACC[i][j]); \
        __syncthreads();                                                              \
        buf ^= 1;                                                                     \
    }

// ---------- fused q/k/v projections, coalesced epilogue via LDS ----------
__global__ __launch_bounds__(256) void k_proj(
    const u16* __restrict__ qb, const u16* __restrict__ kb, const u16* __restrict__ vb,
    const u16* __restrict__ wqt, const u16* __restrict__ wkt, const u16* __restrict__ wvt,
    u16* __restrict__ oq, u16* __restrict__ okh, u16* __restrict__ ovt) {
    __shared__ __align__(16) u16 smem[18432];
    u16* As = smem;
    u16* Bs = smem + 8192;
    int z = blockIdx.y, gx = blockIdx.x;
    int bm, bn;
    const u16 *A, *B;
    if (z == 0)      { bm = gx >> 3; bn = gx & 7; A = qb; B = wqt; }
    else if (z == 1) { bm = gx >> 3; bn = gx & 7; A = kb; B = wkt; }
    else             { bm = gx & 7; bn = gx >> 3; A = wvt; B = vb; }
    A += (size_t)bm * 128 * 1024;
    B += (size_t)bn * 128 * 1024;
    int tid = threadIdx.x, wave = tid >> 6, lane = tid & 63;
    int wy = wave >> 1, wx = wave & 1, l15 = lane & 15, quad = lane >> 4;
    f32x4 acc[4][4] = {};
    GEMM_CORE(A, B, acc)
    u16* ep = smem + wave * 4608;
    float mulf = (z == 0) ? 0.18033688011112042f : 1.0f;
#pragma unroll
    for (int i = 0; i < 4; ++i)
#pragma unroll
        for (int j = 0; j < 4; ++j)
#pragma unroll
            for (int r = 0; r < 4; ++r)
                ep[(i * 16 + quad * 4 + r) * 72 + j * 16 + l15] = f2bf(acc[i][j][r] * mulf);
    int rl = lane >> 3, cg = lane & 7;
    if (z < 2) {
        int hh = bn * 2 + wx;
        int m0 = bm * 128 + wy * 64;
        int bb = m0 >> 11, l0 = m0 & 2047;
        u16* O = (z ? okh : oq) + ((size_t)((hh * 2 + bb) * 2048 + l0)) * 64;
#pragma unroll
        for (int s = 0; s < 8; ++s) {
            int row = s * 8 + rl;
            uint4 v = *(const uint4*)(ep + row * 72 + cg * 8);
            *(uint4*)(O + (size_t)row * 64 + cg * 8) = v;
        }
    } else {
        int m0 = bm * 128 + wy * 64;
        int hh = m0 >> 6;
        int n0 = bn * 128 + wx * 64;
        int bb = n0 >> 11, l0 = n0 & 2047;
        u16* O = ovt + (size_t)(hh * 2 + bb) * 131072 + (size_t)(m0 & 63) * 2048 + l0;
#pragma unroll
        for (int s = 0; s < 8; ++s) {
            int row = s * 8 + rl;
            uint4 v = *(const uint4*)(ep + row * 72 + cg * 8);
            *(uint4*)(O + (size_t)row * 2048 + cg * 8) = v;
        }
    }
}

// ---------- flash attention: split-K=2, 256 thr (4 waves x 32 Q-rows), swizzled Pb ----------
// grid (16 qt, 32 hb, 2 ks); LDS exactly 40960 B -> 4 blocks/CU = 16 waves/CU
__global__ __launch_bounds__(256) void k_attn(
    const u16* __restrict__ qh, const u16* __restrict__ kh,
    const u16* __restrict__ vt, const u64* __restrict__ mask64,
    u16* __restrict__ po, float* __restrict__ pl) {
    int qt = blockIdx.x, hb = blockIdx.y, ksp = blockIdx.z;
    int b = hb & 1;
    int tid = threadIdx.x, wave = tid >> 6, lane = tid & 63;
    int l15 = lane & 15, quad = lane >> 4;

    __shared__ __align__(16) u16 Ks[2][4096], Vs[2][4096];
    __shared__ __align__(16) u16 Pb[4][1024];   // 16 rows x 64 cols, XOR-swizzled groups

    int qrow0 = qt * 128 + wave * 32;
    const u16* Qp = qh + ((size_t)(hb * 2048) + qrow0 + l15) * 64 + quad * 8;
    bf16x8 qf[2][2];
    qf[0][0] = *(const bf16x8*)Qp;
    qf[0][1] = *(const bf16x8*)(Qp + 32);
    qf[1][0] = *(const bf16x8*)(Qp + 1024);
    qf[1][1] = *(const bf16x8*)(Qp + 1024 + 32);

    // staging: wave stages chunks 2w, 2w+1 (chunk c: K rows (c>>1)*16, dcols (c&1)*32)
    int c0 = wave * 2;
    const u16* Kg0 = kh + (size_t)hb * 131072 + (size_t)ksp * 65536 +
                     (size_t)(wave * 16 + l15) * 64 + quad * 8;
    const u16* Kg1 = Kg0 + 32;
    const u16* Vg0 = vt + (size_t)hb * 131072 + (size_t)(wave * 16 + l15) * 2048 +
                     ksp * 1024 + quad * 8;
    const u16* Vg1 = Vg0 + 32;
    const u64* Mp = mask64 + (size_t)b * 65536 + (size_t)ksp * 32768 + qrow0 + l15;

    float l_lane[2] = {0.f, 0.f};
    f32x4 o[2][4] = {};

    gld16(Kg0, &Ks[0][c0 * 512]);
    gld16(Kg1, &Ks[0][(c0 + 1) * 512]);
    gld16(Vg0, &Vs[0][c0 * 512]);
    gld16(Vg1, &Vs[0][(c0 + 1) * 512]);
    u64 mw0 = Mp[0], mw1 = Mp[16];
    __syncthreads();
    int buf = 0;
    int swz = (l15 & 7) << 3;               // XOR key (u16 units) for Pb groups
    for (int kt = 0; kt < 16; ++kt) {
        u64 mwn0 = 0, mwn1 = 0;
        if (kt < 15) {
            gld16(Kg0 + (size_t)(kt + 1) * 4096, &Ks[buf ^ 1][c0 * 512]);
            gld16(Kg1 + (size_t)(kt + 1) * 4096, &Ks[buf ^ 1][(c0 + 1) * 512]);
            gld16(Vg0 + (size_t)(kt + 1) * 64, &Vs[buf ^ 1][c0 * 512]);
            gld16(Vg1 + (size_t)(kt + 1) * 64, &Vs[buf ^ 1][(c0 + 1) * 512]);
            mwn0 = Mp[(size_t)(kt + 1) * 2048];
            mwn1 = Mp[(size_t)(kt + 1) * 2048 + 16];
        }
        bf16x8 kf[8], vf[8];
#pragma unroll
        for (int c = 0; c < 8; ++c) kf[c] = *(const bf16x8*)&Ks[buf][c * 512 + lane * 8];
#pragma unroll
        for (int c = 0; c < 8; ++c) vf[c] = *(const bf16x8*)&Vs[buf][c * 512 + lane * 8];
#pragma unroll
        for (int hf = 0; hf < 2; ++hf) {
            u64 mw = hf ? mw1 : mw0;
            f32x4 st[4] = {};
#pragma unroll
            for (int t = 0; t < 4; ++t) {
                st[t] = MFMA16(kf[t * 2], qf[hf][0], st[t]);
                st[t] = MFMA16(kf[t * 2 + 1], qf[hf][1], st[t]);
            }
            unsigned int w0 = (unsigned int)(mw >> (quad * 4));
            unsigned int w1 = (unsigned int)(mw >> (32 + quad * 4));
#pragma unroll
            for (int r = 0; r < 4; ++r) {
                st[0][r] = ((w0 >> r) & 1u) ? -3e30f : st[0][r];
                st[1][r] = ((w0 >> (16 + r)) & 1u) ? -3e30f : st[1][r];
                st[2][r] = ((w1 >> r) & 1u) ? -3e30f : st[2][r];
                st[3][r] = ((w1 >> (16 + r)) & 1u) ? -3e30f : st[3][r];
            }
            float ll = 0.f;
#pragma unroll
            for (int t = 0; t < 4; ++t) {
                float p0 = __builtin_amdgcn_exp2f(st[t][0]);
                float p1 = __builtin_amdgcn_exp2f(st[t][1]);
                float p2 = __builtin_amdgcn_exp2f(st[t][2]);
                float p3 = __builtin_amdgcn_exp2f(st[t][3]);
                ll += (p0 + p1) + (p2 + p3);
                uint2 pk;
                pk.x = (__float_as_uint(p1) & 0xffff0000u) | (__float_as_uint(p0) >> 16);
                pk.y = (__float_as_uint(p3) & 0xffff0000u) | (__float_as_uint(p2) >> 16);
                // write: logical (row=l15, cols t*16+quad*4..+3); group g = t*2+(quad>>1)
                int g = t * 2 + (quad >> 1);
                int phys = l15 * 64 + (((g << 3) ^ swz)) + (quad & 1) * 4;
                *(uint2*)&Pb[wave][phys] = pk;
            }
            l_lane[hf] += ll;
#pragma unroll
            for (int kc = 0; kc < 2; ++kc) {
                int g = kc * 4 + quad;
                bf16x8 pf = *(const bf16x8*)&Pb[wave][l15 * 64 + (((g << 3) ^ swz))];
#pragma unroll
                for (int t = 0; t < 4; ++t)
                    o[hf][t] = MFMA16(pf, vf[t * 2 + kc], o[hf][t]);
            }
        }
        mw0 = mwn0; mw1 = mwn1;
        __syncthreads();
        buf ^= 1;
    }
    // ---- store partial l + unnormalized partial O (coalesced via swizzled Pb) ----
    size_t rowbase = ((size_t)ksp * 32 + hb) * 2048 + qrow0;
    int rl = lane >> 3, cg = lane & 7;
#pragma unroll
    for (int hf = 0; hf < 2; ++hf) {
        float ls = l_lane[hf];
        ls += __shfl_xor(ls, 16, 64);
        ls += __shfl_xor(ls, 32, 64);
        if (quad == 0) pl[rowbase + hf * 16 + l15] = ls;
#pragma unroll
        for (int t = 0; t < 4; ++t)
#pragma unroll
            for (int r = 0; r < 4; ++r) {
                int row = quad * 4 + r, col = t * 16 + l15;
                int g = col >> 3;
                Pb[wave][row * 64 + (((g ^ (row & 7)) << 3)) + (col & 7)] =
                    f2bf(o[hf][t][r]);
            }
#pragma unroll
        for (int s = 0; s < 2; ++s) {
            int row = s * 8 + rl;
            uint4 v = *(const uint4*)&Pb[wave][row * 64 + ((cg ^ (row & 7)) << 3)];
            *(uint4*)(po + (rowbase + hf * 16 + row) * 64 + cg * 8) = v;
        }
    }
}

// ---------- split-K merge: ao = (po0+po1)/(l0+l1) ----------
__global__ __launch_bounds__(256) void k_amerge(const u16* __restrict__ po,
                                                const float* __restrict__ pl,
                                                u16* __restrict__ ao) {
    int bid = blockIdx.x;               // 32 hb x 64 row-chunks
    int hb = bid >> 6, rc = bid & 63;
    int h = hb >> 1, b = hb & 1;
    int tid = threadIdx.x;
    int r = tid >> 3, c = tid & 7;
    int row = rc * 32 + r;
    size_t i0 = ((size_t)hb * 2048 + row) * 64 + c * 8;
    uint4 a0 = *(const uint4*)(po + i0);
    uint4 a1 = *(const uint4*)(po + i0 + 4194304);
    float l0 = pl[(size_t)hb * 2048 + row];
    float l1 = pl[65536 + (size_t)hb * 2048 + row];
    float inv = 1.0f / (l0 + l1);
    unsigned int* pa0 = (unsigned int*)&a0;
    unsigned int* pa1 = (unsigned int*)&a1;
    uint4 out;
    unsigned int* po_ = (unsigned int*)&out;
#pragma unroll
    for (int i = 0; i < 4; ++i) {
        float lo = (bf2f(pa0[i] & 0xffffu) + bf2f(pa1[i] & 0xffffu)) * inv;
        float hi = (bf2f(pa0[i] >> 16) + bf2f(pa1[i] >> 16)) * inv;
        po_[i] = (unsigned int)f2bf(lo) | ((unsigned int)f2bf(hi) << 16);
    }
    *(uint4*)(ao + ((size_t)(b * 2048 + row)) * 1024 + h * 64 + c * 8) = out;
}

// ---------- output projection, split-K=2, raw fp32 partials ----------
// grid (256 tiles, 2 ks), 512 thr = 8 waves (2x4), 128x128 tile, K=512 per block
__global__ __launch_bounds__(512) void k_out(
    const u16* __restrict__ ao, const u16* __restrict__ wot,
    float* __restrict__ xp0, float* __restrict__ xp1) {
    __shared__ __align__(16) u16 smem[18432];
    u16* As = smem;
    u16* Bs = smem + 8192;
    int gx = blockIdx.x, bm = gx >> 3, bn = gx & 7;
    int ksp = blockIdx.y;
    const u16* A = ao + (size_t)bm * 128 * 1024 + ksp * 512;
    const u16* B = wot + (size_t)bn * 128 * 1024 + ksp * 512;
    float* xp = ksp ? xp1 : xp0;
    int tid = threadIdx.x, wave = tid >> 6, lane = tid & 63;
    int wy = wave >> 2, wx = wave & 3, l15 = lane & 15, quad = lane >> 4;
    const u16* Ag = A + (size_t)(wave * 16 + l15) * 1024 + quad * 8;
    const u16* Bg = B + (size_t)(wave * 16 + l15) * 1024 + quad * 8;
    f32x4 acc[4][2] = {};
    gld16(Ag, As + wave * 512);
    gld16(Bg, Bs + wave * 512);
    __syncthreads();
    int buf = 0;
    for (int ks = 0; ks < 16; ++ks) {
        if (ks < 15) {
            int k0 = (ks + 1) * 32;
            gld16(Ag + k0, As + (buf ^ 1) * 4096 + wave * 512);
            gld16(Bg + k0, Bs + (buf ^ 1) * 4096 + wave * 512);
        }
        bf16x8 af[4], bfr[2];
#pragma unroll
        for (int i = 0; i < 4; ++i)
            af[i] = *(const bf16x8*)(As + buf * 4096 + (wy * 4 + i) * 512 + lane * 8);
#pragma unroll
        for (int j = 0; j < 2; ++j)
            bfr[j] = *(const bf16x8*)(Bs + buf * 4096 + (wx * 2 + j) * 512 + lane * 8);
#pragma unroll
        for (int i = 0; i < 4; ++i)
#pragma unroll
            for (int j = 0; j < 2; ++j) acc[i][j] = MFMA16(af[i], bfr[j], acc[i][j]);
        __syncthreads();
        buf ^= 1;
    }
    // epilogue: per wave 64x32 fp32, two passes of 32x32 via LDS (stride 36 f32)
    float* epf = (float*)smem + wave * 1152;
    int rl = lane >> 3, cg = lane & 7;
    int mbase = bm * 128 + wy * 64, nbase = bn * 128 + wx * 32;
#pragma unroll
    for (int cc = 0; cc < 2; ++cc) {
#pragma unroll
        for (int i2 = 0; i2 < 2; ++i2)
#pragma unroll
            for (int j = 0; j < 2; ++j)
#pragma unroll
                for (int r = 0; r < 4; ++r)
                    epf[(i2 * 16 + quad * 4 + r) * 36 + j * 16 + l15] =
                        acc[cc * 2 + i2][j][r];
#pragma unroll
        for (int s = 0; s < 4; ++s) {
            int row = s * 8 + rl;
            f32x4 v = *(const f32x4*)(epf + row * 36 + cg * 4);
            int m = mbase + cc * 32 + row, n = nbase + cg * 4;
            *(f32x4*)(xp + (size_t)m * 1024 + n) = v;
        }
    }
}

// ---------- layernorm + split-K sum + bias + residual ----------
__global__ __launch_bounds__(256) void k_ln(const float* __restrict__ xp0,
                                            const float* __restrict__ xp1,
                                            const float* __restrict__ resid,
                                            const float* __restrict__ bo,
                                            const float* __restrict__ gamma,
                                            const float* __restrict__ beta,
                                            float* __restrict__ out) {
    int row = blockIdx.x;
    size_t base = (size_t)row * 256;
    float4 a0 = ((const float4*)xp0)[base + threadIdx.x];
    float4 a1 = ((const float4*)xp1)[base + threadIdx.x];
    float4 rs = ((const float4*)resid)[base + threadIdx.x];
    float4 b4 = ((const float4*)bo)[threadIdx.x];
    float4 v;
    v.x = a0.x + a1.x + rs.x + b4.x;
    v.y = a0.y + a1.y + rs.y + b4.y;
    v.z = a0.z + a1.z + rs.z + b4.z;
    v.w = a0.w + a1.w + rs.w + b4.w;
    float s = v.x + v.y + v.z + v.w;
    float ss = v.x * v.x + v.y * v.y + v.z * v.z + v.w * v.w;
#pragma unroll
    for (int off = 32; off; off >>= 1) {
        s += __shfl_down(s, off, 64);
        ss += __shfl_down(ss, off, 64);
    }
    __shared__ float sb[8];
    int wave = threadIdx.x >> 6, lane = threadIdx.x & 63;
    if (lane == 0) { sb[wave] = s; sb[4 + wave] = ss; }
    __syncthreads();
    s = sb[0] + sb[1] + sb[2] + sb[3];
    ss = sb[4] + sb[5] + sb[6] + sb[7];
    float mean = s * (1.0f / 1024.0f);
    float var = fmaxf((ss - 1024.0f * mean * mean) * (1.0f / 1023.0f), 0.f);
    float inv = 1.0f / (sqrtf(var) + 1e-3f);
    float4 g = ((const float4*)gamma)[threadIdx.x];
    float4 bt = ((const float4*)beta)[threadIdx.x];
    float4 o;
    o.x = (v.x - mean) * inv * g.x + bt.x;
    o.y = (v.y - mean) * inv * g.y + bt.y;
    o.z = (v.z - mean) * inv * g.z + bt.z;
    o.w = (v.w - mean) * inv * g.w + bt.w;
    ((float4*)(out))[base + threadIdx.x] = o;
}

// ---------- launch ----------
extern "C" void kernel_launch(void* const* d_in, const int* in_sizes, int n_in,
                              void* d_out, int out_size, void* d_ws, size_t ws_size,
                              hipStream_t stream) {
    const float* v_in  = (const float*)d_in[0];
    const float* k_in  = (const float*)d_in[1];
    const float* q_in  = (const float*)d_in[2];
    const int*   mask  = (const int*)d_in[3];
    const float* w_q   = (const float*)d_in[4];
    const float* w_k   = (const float*)d_in[5];
    const float* w_v   = (const float*)d_in[6];
    const float* w_o   = (const float*)d_in[7];
    const float* b_o   = (const float*)d_in[8];
    const float* gamma = (const float*)d_in[9];
    const float* beta  = (const float*)d_in[10];
    float* out = (float*)d_out;

    char* ws = (char*)d_ws;
    const size_t MB = 1ull << 20;
    u16* qb  = (u16*)(ws + 0 * MB);
    u16* kb  = (u16*)(ws + 8 * MB);
    u16* vb  = (u16*)(ws + 16 * MB);
    u16* wqt = (u16*)(ws + 24 * MB);
    u16* wkt = (u16*)(ws + 26 * MB);
    u16* wvt = (u16*)(ws + 28 * MB);
    u16* wot = (u16*)(ws + 30 * MB);
    u16* qh  = (u16*)(ws + 32 * MB);
    u16* kh  = (u16*)(ws + 40 * MB);
    u16* vt  = (u16*)(ws + 48 * MB);
    u16* ao  = (u16*)(ws + 56 * MB);
    u64* mask64 = (u64*)(ws + 64 * MB);
    u16*   po = (u16*)(ws + 0 * MB);     // over qb/kb (dead after k_proj)
    float* pl = (float*)(ws + 16 * MB);  // over vb (dead after k_proj)
    float* xp0 = (float*)(ws + 32 * MB); // over qh/kh (dead after k_attn)
    float* xp1 = (float*)(ws + 64 * MB); // over mask64 (dead after k_attn)

    k_prep<<<dim3(20480), dim3(256), 0, stream>>>(q_in, k_in, v_in, mask,
                                                  qb, kb, vb, mask64);
    k_prepw<<<dim3(4096), dim3(256), 0, stream>>>(w_q, w_k, w_v, w_o,
                                                  wqt, wkt, wvt, wot);
    k_proj<<<dim3(256, 3), dim3(256), 0, stream>>>(qb, kb, vb, wqt, wkt, wvt, qh, kh, vt);
    k_attn<<<dim3(16, 32, 2), dim3(256), 0, stream>>>(qh, kh, vt, mask64, po, pl);
    k_amerge<<<dim3(2048), dim3(256), 0, stream>>>(po, pl, ao);
    k_out<<<dim3(256, 2), dim3(512), 0, stream>>>(ao, wot, xp0, xp1);
    k_ln<<<dim3(4096), dim3(256), 0, stream>>>(xp0, xp1, k_in, b_o, gamma, beta, out);
}

// Round 8
// 301.011 us; speedup vs baseline: 1.0345x; 1.0262x over previous
//
#include <hip/hip_runtime.h>
#include <math.h>

// ---------- types ----------
typedef __bf16 bf16_t;
typedef bf16_t bf16x8 __attribute__((ext_vector_type(8)));
typedef float  f32x4  __attribute__((ext_vector_type(4)));
typedef unsigned short u16;
typedef u16 ushortx4 __attribute__((ext_vector_type(4)));
typedef unsigned long long u64;

#define MFMA16(a, b, c) __builtin_amdgcn_mfma_f32_16x16x32_bf16((a), (b), (c), 0, 0, 0)

__device__ __forceinline__ u16 f2bf(float f) {
    unsigned int u = __float_as_uint(f);
    u = (u + 0x7fffu + ((u >> 16) & 1u)) >> 16;
    return (u16)u;
}

__device__ __forceinline__ float bf2f(unsigned int u) {
    return __uint_as_float(u << 16);
}

// async global->LDS, 16B per lane; lds dest = wave-uniform base + lane*16
__device__ __forceinline__ void gld16(const u16* g, u16* l) {
    __builtin_amdgcn_global_load_lds(
        (const __attribute__((address_space(1))) void*)g,
        (__attribute__((address_space(3))) void*)l, 16, 0, 0);
}

// B=2, L=2048, D_MODEL=1024, H=16, DH=64, HB=32
// ws map (MB):  [phase-aware reuse]
//  qb 0-8, kb 8-16, vb 16-24        (dead after k_proj)
//  wqt 24-26 wkt 26-28 wvt 28-30    (dead after k_proj)
//  wot 30-32                        (alive until k_out)
//  qh 32-40 (scaled by log2e/8), kh 40-48, vt 48-56 (dead after k_attn)
//  ao 56-64                          (alive until k_out)
//  mask64 64-65                      (dead after k_attn)
//  po 0-16 (over qb/kb), pl 16-17 (over vb)   [k_attn out, dead after k_amerge]
//  xp0 32-48 (over qh/kh), xp1 64-80 (over mask64)  [k_out partials -> k_ln]

// ---------- fused: fp32->bf16 cvt for q,k,v + mask bit-pack + weight transposes ----------
__global__ __launch_bounds__(256) void k_prep(const float* __restrict__ q,
                                              const float* __restrict__ k,
                                              const float* __restrict__ v,
                                              const int* __restrict__ mask,
                                              const float* __restrict__ w_q,
                                              const float* __restrict__ w_k,
                                              const float* __restrict__ w_v,
                                              const float* __restrict__ w_o,
                                              u16* __restrict__ qb,
                                              u16* __restrict__ kb,
                                              u16* __restrict__ vb,
                                              u64* __restrict__ mask64,
                                              u16* __restrict__ wqt,
                                              u16* __restrict__ wkt,
                                              u16* __restrict__ wvt,
                                              u16* __restrict__ wot) {
    __shared__ float tile[32][33];
    int bid = blockIdx.x;
    if (bid < 12288) {
        int sel = bid >> 12;                 // 0..2
        int i = (bid & 4095) * 256 + threadIdx.x;
        const float* src = sel == 0 ? q : (sel == 1 ? k : v);
        u16* dst = sel == 0 ? qb : (sel == 1 ? kb : vb);
        float4 val = ((const float4*)src)[i];
        ushortx4 r;
        r[0] = f2bf(val.x); r[1] = f2bf(val.y); r[2] = f2bf(val.z); r[3] = f2bf(val.w);
        ((ushortx4*)dst)[i] = r;
    } else if (bid < 20480) {
        int b2 = bid - 12288;                // 2 b x 512 q4 x 8 ktg
        int ktg = b2 & 7, q4 = (b2 >> 3) & 511, b = b2 >> 12;
        int wave = threadIdx.x >> 6, lane = threadIdx.x & 63;
        int qq = q4 * 4 + wave;
        const int* mp = mask + ((size_t)(b * 2048 + qq)) * 2048 + ktg * 256 + lane;
#pragma unroll
        for (int i = 0; i < 4; ++i) {
            int m = mp[i * 64];
            u64 bal = __ballot(m != 0);
            if (lane == 0) mask64[((size_t)(b * 32 + ktg * 4 + i)) * 2048 + qq] = bal;
        }
    } else {
        int b3 = bid - 20480;
        const float* src;
        u16* dst;
        int r0, c0, C;
        if (b3 < 3072) {
            int x = b3 & 31, y = (b3 >> 5) & 1, z = b3 >> 6;
            int h = z & 15, sel = z >> 4;
            src = (sel == 0 ? w_q : (sel == 1 ? w_k : w_v)) + (size_t)h * 65536;
            dst = (sel == 0 ? wqt : (sel == 1 ? wkt : wvt)) + (size_t)h * 65536;
            r0 = x * 32; c0 = y * 32; C = 64;
        } else {
            int t = b3 - 3072;
            r0 = (t & 31) * 32; c0 = (t >> 5) * 32; C = 1024;
            src = w_o; dst = wot;
        }
        int tx = threadIdx.x & 31, ty = threadIdx.x >> 5;
        const float* s = src + ((size_t)r0) * C + c0;
#pragma unroll
        for (int i = 0; i < 4; ++i) tile[ty + i * 8][tx] = s[(ty + i * 8) * (size_t)C + tx];
        __syncthreads();
        u16* d = dst + ((size_t)c0) * 1024 + r0;
#pragma unroll
        for (int i = 0; i < 4; ++i) d[(ty + i * 8) * 1024 + tx] = f2bf(tile[tx][ty + i * 8]);
    }
}

// ---------- GEMM core body (uses As, Bs u16* into shared) ----------
#define GEMM_CORE(Ablk, Bblk, ACC)                                                    \
    int c0 = wave * 2;                                                                \
    const u16* Ag0 = Ablk + (size_t)(c0 * 16 + l15) * 1024 + quad * 8;                \
    const u16* Ag1 = Ablk + (size_t)((c0 + 1) * 16 + l15) * 1024 + quad * 8;          \
    const u16* Bg0 = Bblk + (size_t)(c0 * 16 + l15) * 1024 + quad * 8;                \
    const u16* Bg1 = Bblk + (size_t)((c0 + 1) * 16 + l15) * 1024 + quad * 8;          \
    gld16(Ag0, As + c0 * 512); gld16(Ag1, As + (c0 + 1) * 512);                       \
    gld16(Bg0, Bs + c0 * 512); gld16(Bg1, Bs + (c0 + 1) * 512);                       \
    __syncthreads();                                                                  \
    int buf = 0;                                                                      \
    for (int ks = 0; ks < 32; ++ks) {                                                 \
        if (ks < 31) {                                                                \
            int k0 = (ks + 1) * 32;                                                   \
            gld16(Ag0 + k0, As + (buf ^ 1) * 4096 + c0 * 512);                        \
            gld16(Ag1 + k0, As + (buf ^ 1) * 4096 + (c0 + 1) * 512);                  \
            gld16(Bg0 + k0, Bs + (buf ^ 1) * 4096 + c0 * 512);                        \
            gld16(Bg1 + k0, Bs + (buf ^ 1) * 4096 + (c0 + 1) * 512);                  \
        }                                                                             \
        bf16x8 af[4], bfr[4];                                                         \
        _Pragma("unroll")                                                             \
        for (int i = 0; i < 4; ++i)                                                   \
            af[i] = *(const bf16x8*)(As + buf * 4096 + (wy * 4 + i) * 512 + lane * 8);\
        _Pragma("unroll")                                                             \
        for (int j = 0; j < 4; ++j)                                                   \
            bfr[j] = *(const bf16x8*)(Bs + buf * 4096 + (wx * 4 + j) * 512 + lane * 8);\
        _Pragma("unroll")                                                             \
        for (int i = 0; i < 4; ++i)                                                   \
            _Pragma("unroll")                                                         \
            for (int j = 0; j < 4; ++j) ACC[i][j] = MFMA16(af[i], bfr[j], ACC[i][j]); \
        __syncthreads();                                                              \
        buf ^= 1;                                                                     \
    }

// ---------- fused q/k/v projections, XCD-local A-tile reuse ----------
__global__ __launch_bounds__(256) void k_proj(
    const u16* __restrict__ qb, const u16* __restrict__ kb, const u16* __restrict__ vb,
    const u16* __restrict__ wqt, const u16* __restrict__ wkt, const u16* __restrict__ wvt,
    u16* __restrict__ oq, u16* __restrict__ okh, u16* __restrict__ ovt) {
    __shared__ __align__(16) u16 smem[18432];
    u16* As = smem;
    u16* Bs = smem + 8192;
    int z = blockIdx.y, gx = blockIdx.x;
    int bm, bn;
    const u16 *A, *B;
    // fastest-varying index = tile of the LARGE matrix -> its readers co-locate per XCD
    if (z == 0)      { bm = gx & 31; bn = gx >> 5; A = qb; B = wqt; }
    else if (z == 1) { bm = gx & 31; bn = gx >> 5; A = kb; B = wkt; }
    else             { bn = gx & 31; bm = gx >> 5; A = wvt; B = vb; }
    A += (size_t)bm * 128 * 1024;
    B += (size_t)bn * 128 * 1024;
    int tid = threadIdx.x, wave = tid >> 6, lane = tid & 63;
    int wy = wave >> 1, wx = wave & 1, l15 = lane & 15, quad = lane >> 4;
    f32x4 acc[4][4] = {};
    GEMM_CORE(A, B, acc)
    u16* ep = smem + wave * 4608;
    float mulf = (z == 0) ? 0.18033688011112042f : 1.0f;
#pragma unroll
    for (int i = 0; i < 4; ++i)
#pragma unroll
        for (int j = 0; j < 4; ++j)
#pragma unroll
            for (int r = 0; r < 4; ++r)
                ep[(i * 16 + quad * 4 + r) * 72 + j * 16 + l15] = f2bf(acc[i][j][r] * mulf);
    int rl = lane >> 3, cg = lane & 7;
    if (z < 2) {
        int hh = bn * 2 + wx;
        int m0 = bm * 128 + wy * 64;
        int bb = m0 >> 11, l0 = m0 & 2047;
        u16* O = (z ? okh : oq) + ((size_t)((hh * 2 + bb) * 2048 + l0)) * 64;
#pragma unroll
        for (int s = 0; s < 8; ++s) {
            int row = s * 8 + rl;
            uint4 v = *(const uint4*)(ep + row * 72 + cg * 8);
            *(uint4*)(O + (size_t)row * 64 + cg * 8) = v;
        }
    } else {
        int m0 = bm * 128 + wy * 64;
        int hh = m0 >> 6;
        int n0 = bn * 128 + wx * 64;
        int bb = n0 >> 11, l0 = n0 & 2047;
        u16* O = ovt + (size_t)(hh * 2 + bb) * 131072 + (size_t)(m0 & 63) * 2048 + l0;
#pragma unroll
        for (int s = 0; s < 8; ++s) {
            int row = s * 8 + rl;
            uint4 v = *(const uint4*)(ep + row * 72 + cg * 8);
            *(uint4*)(O + (size_t)row * 2048 + cg * 8) = v;
        }
    }
}

// ---------- flash attention: split-K=2, hb-fastest grid (XCD-local K/V) ----------
// grid (32 hb, 16 qt, 2 ks); 256 thr = 4 waves x 32 Q-rows; swizzled Pb
__global__ __launch_bounds__(256) void k_attn(
    const u16* __restrict__ qh, const u16* __restrict__ kh,
    const u16* __restrict__ vt, const u64* __restrict__ mask64,
    u16* __restrict__ po, float* __restrict__ pl) {
    int hb = blockIdx.x, qt = blockIdx.y, ksp = blockIdx.z;
    int b = hb & 1;
    int tid = threadIdx.x, wave = tid >> 6, lane = tid & 63;
    int l15 = lane & 15, quad = lane >> 4;

    __shared__ __align__(16) u16 Ks[2][4096], Vs[2][4096];
    __shared__ __align__(16) u16 Pb[4][1024];   // 16 rows x 64 cols, XOR-swizzled groups

    int qrow0 = qt * 128 + wave * 32;
    const u16* Qp = qh + ((size_t)(hb * 2048) + qrow0 + l15) * 64 + quad * 8;
    bf16x8 qf[2][2];
    qf[0][0] = *(const bf16x8*)Qp;
    qf[0][1] = *(const bf16x8*)(Qp + 32);
    qf[1][0] = *(const bf16x8*)(Qp + 1024);
    qf[1][1] = *(const bf16x8*)(Qp + 1024 + 32);

    int c0 = wave * 2;
    const u16* Kg0 = kh + (size_t)hb * 131072 + (size_t)ksp * 65536 +
                     (size_t)(wave * 16 + l15) * 64 + quad * 8;
    const u16* Kg1 = Kg0 + 32;
    const u16* Vg0 = vt + (size_t)hb * 131072 + (size_t)(wave * 16 + l15) * 2048 +
                     ksp * 1024 + quad * 8;
    const u16* Vg1 = Vg0 + 32;
    const u64* Mp = mask64 + (size_t)b * 65536 + (size_t)ksp * 32768 + qrow0 + l15;

    float l_lane[2] = {0.f, 0.f};
    f32x4 o[2][4] = {};

    gld16(Kg0, &Ks[0][c0 * 512]);
    gld16(Kg1, &Ks[0][(c0 + 1) * 512]);
    gld16(Vg0, &Vs[0][c0 * 512]);
    gld16(Vg1, &Vs[0][(c0 + 1) * 512]);
    u64 mw0 = Mp[0], mw1 = Mp[16];
    __syncthreads();
    int buf = 0;
    int swz = (l15 & 7) << 3;               // XOR key (u16 units) for Pb groups
    for (int kt = 0; kt < 16; ++kt) {
        u64 mwn0 = 0, mwn1 = 0;
        if (kt < 15) {
            gld16(Kg0 + (size_t)(kt + 1) * 4096, &Ks[buf ^ 1][c0 * 512]);
            gld16(Kg1 + (size_t)(kt + 1) * 4096, &Ks[buf ^ 1][(c0 + 1) * 512]);
            gld16(Vg0 + (size_t)(kt + 1) * 64, &Vs[buf ^ 1][c0 * 512]);
            gld16(Vg1 + (size_t)(kt + 1) * 64, &Vs[buf ^ 1][(c0 + 1) * 512]);
            mwn0 = Mp[(size_t)(kt + 1) * 2048];
            mwn1 = Mp[(size_t)(kt + 1) * 2048 + 16];
        }
        bf16x8 kf[8], vf[8];
#pragma unroll
        for (int c = 0; c < 8; ++c) kf[c] = *(const bf16x8*)&Ks[buf][c * 512 + lane * 8];
#pragma unroll
        for (int c = 0; c < 8; ++c) vf[c] = *(const bf16x8*)&Vs[buf][c * 512 + lane * 8];
#pragma unroll
        for (int hf = 0; hf < 2; ++hf) {
            u64 mw = hf ? mw1 : mw0;
            f32x4 st[4] = {};
#pragma unroll
            for (int t = 0; t < 4; ++t) {
                st[t] = MFMA16(kf[t * 2], qf[hf][0], st[t]);
                st[t] = MFMA16(kf[t * 2 + 1], qf[hf][1], st[t]);
            }
            unsigned int w0 = (unsigned int)(mw >> (quad * 4));
            unsigned int w1 = (unsigned int)(mw >> (32 + quad * 4));
#pragma unroll
            for (int r = 0; r < 4; ++r) {
                st[0][r] = ((w0 >> r) & 1u) ? -3e30f : st[0][r];
                st[1][r] = ((w0 >> (16 + r)) & 1u) ? -3e30f : st[1][r];
                st[2][r] = ((w1 >> r) & 1u) ? -3e30f : st[2][r];
                st[3][r] = ((w1 >> (16 + r)) & 1u) ? -3e30f : st[3][r];
            }
            float ll = 0.f;
#pragma unroll
            for (int t = 0; t < 4; ++t) {
                float p0 = __builtin_amdgcn_exp2f(st[t][0]);
                float p1 = __builtin_amdgcn_exp2f(st[t][1]);
                float p2 = __builtin_amdgcn_exp2f(st[t][2]);
                float p3 = __builtin_amdgcn_exp2f(st[t][3]);
                ll += (p0 + p1) + (p2 + p3);
                uint2 pk;
                pk.x = (__float_as_uint(p1) & 0xffff0000u) | (__float_as_uint(p0) >> 16);
                pk.y = (__float_as_uint(p3) & 0xffff0000u) | (__float_as_uint(p2) >> 16);
                int g = t * 2 + (quad >> 1);
                int phys = l15 * 64 + (((g << 3) ^ swz)) + (quad & 1) * 4;
                *(uint2*)&Pb[wave][phys] = pk;
            }
            l_lane[hf] += ll;
#pragma unroll
            for (int kc = 0; kc < 2; ++kc) {
                int g = kc * 4 + quad;
                bf16x8 pf = *(const bf16x8*)&Pb[wave][l15 * 64 + (((g << 3) ^ swz))];
#pragma unroll
                for (int t = 0; t < 4; ++t)
                    o[hf][t] = MFMA16(pf, vf[t * 2 + kc], o[hf][t]);
            }
        }
        mw0 = mwn0; mw1 = mwn1;
        __syncthreads();
        buf ^= 1;
    }
    // ---- store partial l + unnormalized partial O (coalesced via swizzled Pb) ----
    size_t rowbase = ((size_t)ksp * 32 + hb) * 2048 + qrow0;
    int rl = lane >> 3, cg = lane & 7;
#pragma unroll
    for (int hf = 0; hf < 2; ++hf) {
        float ls = l_lane[hf];
        ls += __shfl_xor(ls, 16, 64);
        ls += __shfl_xor(ls, 32, 64);
        if (quad == 0) pl[rowbase + hf * 16 + l15] = ls;
#pragma unroll
        for (int t = 0; t < 4; ++t)
#pragma unroll
            for (int r = 0; r < 4; ++r) {
                int row = quad * 4 + r, col = t * 16 + l15;
                int g = col >> 3;
                Pb[wave][row * 64 + (((g ^ (row & 7)) << 3)) + (col & 7)] =
                    f2bf(o[hf][t][r]);
            }
#pragma unroll
        for (int s = 0; s < 2; ++s) {
            int row = s * 8 + rl;
            uint4 v = *(const uint4*)&Pb[wave][row * 64 + ((cg ^ (row & 7)) << 3)];
            *(uint4*)(po + (rowbase + hf * 16 + row) * 64 + cg * 8) = v;
        }
    }
}

// ---------- split-K merge: ao = (po0+po1)/(l0+l1) ----------
__global__ __launch_bounds__(256) void k_amerge(const u16* __restrict__ po,
                                                const float* __restrict__ pl,
                                                u16* __restrict__ ao) {
    int bid = blockIdx.x;               // 32 hb x 64 row-chunks
    int hb = bid >> 6, rc = bid & 63;
    int h = hb >> 1, b = hb & 1;
    int tid = threadIdx.x;
    int r = tid >> 3, c = tid & 7;
    int row = rc * 32 + r;
    size_t i0 = ((size_t)hb * 2048 + row) * 64 + c * 8;
    uint4 a0 = *(const uint4*)(po + i0);
    uint4 a1 = *(const uint4*)(po + i0 + 4194304);
    float l0 = pl[(size_t)hb * 2048 + row];
    float l1 = pl[65536 + (size_t)hb * 2048 + row];
    float inv = 1.0f / (l0 + l1);
    unsigned int* pa0 = (unsigned int*)&a0;
    unsigned int* pa1 = (unsigned int*)&a1;
    uint4 out;
    unsigned int* po_ = (unsigned int*)&out;
#pragma unroll
    for (int i = 0; i < 4; ++i) {
        float lo = (bf2f(pa0[i] & 0xffffu) + bf2f(pa1[i] & 0xffffu)) * inv;
        float hi = (bf2f(pa0[i] >> 16) + bf2f(pa1[i] >> 16)) * inv;
        po_[i] = (unsigned int)f2bf(lo) | ((unsigned int)f2bf(hi) << 16);
    }
    *(uint4*)(ao + ((size_t)(b * 2048 + row)) * 1024 + h * 64 + c * 8) = out;
}

// ---------- output projection, split-K=2, raw fp32 partials, bm-fastest ----------
__global__ __launch_bounds__(512) void k_out(
    const u16* __restrict__ ao, const u16* __restrict__ wot,
    float* __restrict__ xp0, float* __restrict__ xp1) {
    __shared__ __align__(16) u16 smem[18432];
    u16* As = smem;
    u16* Bs = smem + 8192;
    int gx = blockIdx.x, bm = gx & 31, bn = gx >> 5;
    int ksp = blockIdx.y;
    const u16* A = ao + (size_t)bm * 128 * 1024 + ksp * 512;
    const u16* B = wot + (size_t)bn * 128 * 1024 + ksp * 512;
    float* xp = ksp ? xp1 : xp0;
    int tid = threadIdx.x, wave = tid >> 6, lane = tid & 63;
    int wy = wave >> 2, wx = wave & 3, l15 = lane & 15, quad = lane >> 4;
    const u16* Ag = A + (size_t)(wave * 16 + l15) * 1024 + quad * 8;
    const u16* Bg = B + (size_t)(wave * 16 + l15) * 1024 + quad * 8;
    f32x4 acc[4][2] = {};
    gld16(Ag, As + wave * 512);
    gld16(Bg, Bs + wave * 512);
    __syncthreads();
    int buf = 0;
    for (int ks = 0; ks < 16; ++ks) {
        if (ks < 15) {
            int k0 = (ks + 1) * 32;
            gld16(Ag + k0, As + (buf ^ 1) * 4096 + wave * 512);
            gld16(Bg + k0, Bs + (buf ^ 1) * 4096 + wave * 512);
        }
        bf16x8 af[4], bfr[2];
#pragma unroll
        for (int i = 0; i < 4; ++i)
            af[i] = *(const bf16x8*)(As + buf * 4096 + (wy * 4 + i) * 512 + lane * 8);
#pragma unroll
        for (int j = 0; j < 2; ++j)
            bfr[j] = *(const bf16x8*)(Bs + buf * 4096 + (wx * 2 + j) * 512 + lane * 8);
#pragma unroll
        for (int i = 0; i < 4; ++i)
#pragma unroll
            for (int j = 0; j < 2; ++j) acc[i][j] = MFMA16(af[i], bfr[j], acc[i][j]);
        __syncthreads();
        buf ^= 1;
    }
    float* epf = (float*)smem + wave * 1152;
    int rl = lane >> 3, cg = lane & 7;
    int mbase = bm * 128 + wy * 64, nbase = bn * 128 + wx * 32;
#pragma unroll
    for (int cc = 0; cc < 2; ++cc) {
#pragma unroll
        for (int i2 = 0; i2 < 2; ++i2)
#pragma unroll
            for (int j = 0; j < 2; ++j)
#pragma unroll
                for (int r = 0; r < 4; ++r)
                    epf[(i2 * 16 + quad * 4 + r) * 36 + j * 16 + l15] =
                        acc[cc * 2 + i2][j][r];
#pragma unroll
        for (int s = 0; s < 4; ++s) {
            int row = s * 8 + rl;
            f32x4 v = *(const f32x4*)(epf + row * 36 + cg * 4);
            int m = mbase + cc * 32 + row, n = nbase + cg * 4;
            *(f32x4*)(xp + (size_t)m * 1024 + n) = v;
        }
    }
}

// ---------- layernorm + split-K sum + bias + residual ----------
__global__ __launch_bounds__(256) void k_ln(const float* __restrict__ xp0,
                                            const float* __restrict__ xp1,
                                            const float* __restrict__ resid,
                                            const float* __restrict__ bo,
                                            const float* __restrict__ gamma,
                                            const float* __restrict__ beta,
                                            float* __restrict__ out) {
    int row = blockIdx.x;
    size_t base = (size_t)row * 256;
    float4 a0 = ((const float4*)xp0)[base + threadIdx.x];
    float4 a1 = ((const float4*)xp1)[base + threadIdx.x];
    float4 rs = ((const float4*)resid)[base + threadIdx.x];
    float4 b4 = ((const float4*)bo)[threadIdx.x];
    float4 v;
    v.x = a0.x + a1.x + rs.x + b4.x;
    v.y = a0.y + a1.y + rs.y + b4.y;
    v.z = a0.z + a1.z + rs.z + b4.z;
    v.w = a0.w + a1.w + rs.w + b4.w;
    float s = v.x + v.y + v.z + v.w;
    float ss = v.x * v.x + v.y * v.y + v.z * v.z + v.w * v.w;
#pragma unroll
    for (int off = 32; off; off >>= 1) {
        s += __shfl_down(s, off, 64);
        ss += __shfl_down(ss, off, 64);
    }
    __shared__ float sb[8];
    int wave = threadIdx.x >> 6, lane = threadIdx.x & 63;
    if (lane == 0) { sb[wave] = s; sb[4 + wave] = ss; }
    __syncthreads();
    s = sb[0] + sb[1] + sb[2] + sb[3];
    ss = sb[4] + sb[5] + sb[6] + sb[7];
    float mean = s * (1.0f / 1024.0f);
    float var = fmaxf((ss - 1024.0f * mean * mean) * (1.0f / 1023.0f), 0.f);
    float inv = 1.0f / (sqrtf(var) + 1e-3f);
    float4 g = ((const float4*)gamma)[threadIdx.x];
    float4 bt = ((const float4*)beta)[threadIdx.x];
    float4 o;
    o.x = (v.x - mean) * inv * g.x + bt.x;
    o.y = (v.y - mean) * inv * g.y + bt.y;
    o.z = (v.z - mean) * inv * g.z + bt.z;
    o.w = (v.w - mean) * inv * g.w + bt.w;
    ((float4*)(out))[base + threadIdx.x] = o;
}

// ---------- launch ----------
extern "C" void kernel_launch(void* const* d_in, const int* in_sizes, int n_in,
                              void* d_out, int out_size, void* d_ws, size_t ws_size,
                              hipStream_t stream) {
    const float* v_in  = (const float*)d_in[0];
    const float* k_in  = (const float*)d_in[1];
    const float* q_in  = (const float*)d_in[2];
    const int*   mask  = (const int*)d_in[3];
    const float* w_q   = (const float*)d_in[4];
    const float* w_k   = (const float*)d_in[5];
    const float* w_v   = (const float*)d_in[6];
    const float* w_o   = (const float*)d_in[7];
    const float* b_o   = (const float*)d_in[8];
    const float* gamma = (const float*)d_in[9];
    const float* beta  = (const float*)d_in[10];
    float* out = (float*)d_out;

    char* ws = (char*)d_ws;
    const size_t MB = 1ull << 20;
    u16* qb  = (u16*)(ws + 0 * MB);
    u16* kb  = (u16*)(ws + 8 * MB);
    u16* vb  = (u16*)(ws + 16 * MB);
    u16* wqt = (u16*)(ws + 24 * MB);
    u16* wkt = (u16*)(ws + 26 * MB);
    u16* wvt = (u16*)(ws + 28 * MB);
    u16* wot = (u16*)(ws + 30 * MB);
    u16* qh  = (u16*)(ws + 32 * MB);
    u16* kh  = (u16*)(ws + 40 * MB);
    u16* vt  = (u16*)(ws + 48 * MB);
    u16* ao  = (u16*)(ws + 56 * MB);
    u64* mask64 = (u64*)(ws + 64 * MB);
    u16*   po = (u16*)(ws + 0 * MB);     // over qb/kb (dead after k_proj)
    float* pl = (float*)(ws + 16 * MB);  // over vb (dead after k_proj)
    float* xp0 = (float*)(ws + 32 * MB); // over qh/kh (dead after k_attn)
    float* xp1 = (float*)(ws + 64 * MB); // over mask64 (dead after k_attn)

    k_prep<<<dim3(24576), dim3(256), 0, stream>>>(q_in, k_in, v_in, mask,
                                                  w_q, w_k, w_v, w_o,
                                                  qb, kb, vb, mask64,
                                                  wqt, wkt, wvt, wot);
    k_proj<<<dim3(256, 3), dim3(256), 0, stream>>>(qb, kb, vb, wqt, wkt, wvt, qh, kh, vt);
    k_attn<<<dim3(32, 16, 2), dim3(256), 0, stream>>>(qh, kh, vt, mask64, po, pl);
    k_amerge<<<dim3(2048), dim3(256), 0, stream>>>(po, pl, ao);
    k_out<<<dim3(256, 2), dim3(512), 0, stream>>>(ao, wot, xp0, xp1);
    k_ln<<<dim3(4096), dim3(256), 0, stream>>>(xp0, xp1, k_in, b_o, gamma, beta, out);
}